// Round 13
// baseline (700.887 us; speedup 1.0000x reference)
//
#include <hip/hip_runtime.h>
#include <hip/hip_cooperative_groups.h>
#include <math.h>

namespace cg = cooperative_groups;

#define N_NODES 50000
#define E_EDGES 800000
#define F_IN 100
#define HID 128
#define HEADS 2
#define OUT_C 47
#define HH (HEADS*HID)   // 256
#define MPAD 50048       // N_NODES padded to 128-row tiles
#define NBLK 196         // ceil(N_NODES/256) — scan segments
#define NBGRID 1024      // coop grid: 4 blocks/CU, co-resident at 12 VGPR/1KB LDS

typedef float floatx4 __attribute__((ext_vector_type(4)));
typedef float float2v __attribute__((ext_vector_type(2)));
typedef short short8 __attribute__((ext_vector_type(8)));

__device__ inline ushort bf16round(float v) {
    unsigned u = __float_as_uint(v);
    return (ushort)((u + 0x7FFFu + ((u >> 16) & 1u)) >> 16);
}

// async global->LDS, 16B per lane; LDS dest = wave-uniform base + lane*16
__device__ __forceinline__ void gl_lds16(const void* g, void* l) {
    __builtin_amdgcn_global_load_lds(
        (const __attribute__((address_space(1))) unsigned int*)g,
        (__attribute__((address_space(3))) unsigned int*)l, 16, 0, 0);
}

// ---------------- cooperative CSR build + all converts (single dispatch) -------
// grid = NBGRID x 256 (4 blocks/CU, co-resident). phases:
// 0 zero deg | 1 count+rank atomics + fp32->bf16 converts | 2a block scan
// (blocks 0..NBLK-1) | 2b bsum scan + add | 3 rank-based fill.
__global__ void csr_build(
    const int* __restrict__ dstv, const int* __restrict__ srcv,
    int* __restrict__ deg, ushort* __restrict__ rank,
    int* __restrict__ rowptr, int* __restrict__ bsum, ushort* __restrict__ csr16,
    const float* __restrict__ x,  const float* __restrict__ W0,
    const float* __restrict__ W1, const float* __restrict__ Wp1,
    const float* __restrict__ Wp2,
    ushort* __restrict__ xb,  ushort* __restrict__ W0b,
    ushort* __restrict__ W1b, ushort* __restrict__ Wp1b, ushort* __restrict__ Wp2b)
{
    cg::grid_group grid = cg::this_grid();
    const int t = threadIdx.x;
    const int tid = blockIdx.x * 256 + t;
    const int gsz = NBGRID * 256;

    // phase 0: zero degree counters
    for (int i = tid; i < N_NODES; i += gsz) deg[i] = 0;
    grid.sync();

    // phase 1: edge count + rank; weight/x converts (4-wide)
    for (int e = tid; e < E_EDGES; e += gsz)
        rank[e] = (ushort)atomicAdd(&deg[dstv[e]], 1);
    {
        const int cx = N_NODES * 32;        // x: 32 chunks/row (K 100->128)
        const int c0 = cx + 256 * 32;       // W0
        const int c1 = c0 + (HH * HH) / 4;  // W1
        const int c2 = c1 + (HID * HH) / 4; // Wp1
        const int c3 = c2 + (64 * HID) / 4; // Wp2 (64 padded rows)
        for (int i = tid; i < c3; i += gsz) {
            float4 v = make_float4(0.f, 0.f, 0.f, 0.f);
            ushort* H; size_t o;
            if (i < cx) {
                int row = i >> 5, kc = (i & 31) * 4;
                if (kc < F_IN) v = *(const float4*)(x + (size_t)row * F_IN + kc);
                H = xb; o = (size_t)row * 128 + kc;
            } else if (i < c0) {
                int j = i - cx;
                int row = j >> 5, kc = (j & 31) * 4;
                if (kc < F_IN) v = *(const float4*)(W0 + (size_t)row * F_IN + kc);
                H = W0b; o = (size_t)row * 128 + kc;
            } else if (i < c1) {
                int j = i - c0;
                v = *(const float4*)(W1 + (size_t)j * 4);
                H = W1b; o = (size_t)j * 4;
            } else if (i < c2) {
                int j = i - c1;
                v = *(const float4*)(Wp1 + (size_t)j * 4);
                H = Wp1b; o = (size_t)j * 4;
            } else {
                int j = i - c2;
                int row = j >> 5;
                if (row < OUT_C) v = *(const float4*)(Wp2 + (size_t)j * 4);
                H = Wp2b; o = (size_t)j * 4;
            }
            ushort4 r;
            r.x = bf16round(v.x); r.y = bf16round(v.y);
            r.z = bf16round(v.z); r.w = bf16round(v.w);
            *(ushort4*)(H + o) = r;
        }
    }
    grid.sync();

    // phase 2a: per-block inclusive scan (only first NBLK blocks)
    __shared__ int s[256];
    if (blockIdx.x < NBLK) {
        int i2 = blockIdx.x * 256 + t;
        int v2 = (i2 < N_NODES) ? deg[i2] : 0;
        s[t] = v2;
        __syncthreads();
        for (int off = 1; off < 256; off <<= 1) {
            int add = (t >= off) ? s[t - off] : 0;
            __syncthreads();
            s[t] += add;
            __syncthreads();
        }
        int incl = s[t];
        if (i2 < N_NODES) rowptr[i2] = incl - v2;   // exclusive
        if (t == 255) bsum[blockIdx.x] = incl;
    }
    grid.sync();

    // phase 2b: first NBLK blocks redundantly scan bsum, add prefix
    if (blockIdx.x < NBLK) {
        s[t] = (t < NBLK) ? bsum[t] : 0;
        __syncthreads();
        for (int off = 1; off < 256; off <<= 1) {
            int add = (t >= off) ? s[t - off] : 0;
            __syncthreads();
            s[t] += add;
            __syncthreads();
        }
        int addp = (blockIdx.x == 0) ? 0 : s[blockIdx.x - 1];
        int i2 = blockIdx.x * 256 + t;
        if (i2 < N_NODES) rowptr[i2] += addp;
        if (i2 == 0) rowptr[N_NODES] = E_EDGES;
    }
    grid.sync();

    // phase 3: rank-based fill (no atomics, 2B scatter)
    for (int e = tid; e < E_EDGES; e += gsz) {
        int pos = rowptr[dstv[e]] + (int)rank[e];
        csr16[pos] = (ushort)srcv[e];
    }
}

// ---------------- bf16 MFMA GEMM body (128x128 tile), async LDS staging -------
__device__ __forceinline__ void gemm_body(
    int bx, int by,
    const ushort* __restrict__ Ab, const ushort* __restrict__ Wb,
    const float* __restrict__ bias,
    ushort* __restrict__ Hb,
    const float* __restrict__ attl, const float* __restrict__ attr,
    float* __restrict__ al, float* __restrict__ ar,
    int M, int Kp, ushort* sA, ushort* sB)
{
    const int t = threadIdx.x;
    const int wave = t >> 6, lane = t & 63;
    const int quad = lane >> 4, l16 = lane & 15;
    const int rl = lane >> 2, seg = lane & 3;
    const int m0 = by * 128, n0 = bx * 128;

    floatx4 acc[2][8];
#pragma unroll
    for (int i = 0; i < 2; i++)
#pragma unroll
        for (int j = 0; j < 8; j++) acc[i][j] = (floatx4)(0.f);

    for (int k0 = 0; k0 < Kp; k0 += 32) {
#pragma unroll
        for (int j = 0; j < 2; j++) {
            int br = wave * 32 + j * 16;
            size_t gro = (size_t)(m0 + br + rl) * Kp + k0 + seg * 8;
            gl_lds16(Ab + gro, sA + br * 32);
        }
#pragma unroll
        for (int j = 0; j < 2; j++) {
            int br = wave * 32 + j * 16;
            size_t gro = (size_t)(n0 + br + rl) * Kp + k0 + seg * 8;
            gl_lds16(Wb + gro, sB + br * 32);
        }
        __syncthreads();

        short8 af[2];
#pragma unroll
        for (int sm = 0; sm < 2; sm++) {
            int r = wave * 32 + sm * 16 + l16;
            af[sm] = *(const short8*)(sA + r * 32 + quad * 8);
        }
#pragma unroll
        for (int sn = 0; sn < 8; sn++) {
            int r = sn * 16 + l16;
            short8 b = *(const short8*)(sB + r * 32 + quad * 8);
#pragma unroll
            for (int sm = 0; sm < 2; sm++)
                acc[sm][sn] = __builtin_amdgcn_mfma_f32_16x16x32_bf16(af[sm], b, acc[sm][sn], 0, 0, 0);
        }
        __syncthreads();
    }

    // epilogue: C/D layout col=lane&15, row=quad*4+reg; fused alpha scores
    float bias_r[8], att_l[8], att_r[8];
#pragma unroll
    for (int sn = 0; sn < 8; sn++) {
        int ai = n0 + sn * 16 + l16;
        bias_r[sn] = bias[ai];
        att_l[sn] = attl[ai];
        att_r[sn] = attr[ai];
    }
#pragma unroll
    for (int sm = 0; sm < 2; sm++)
#pragma unroll
        for (int r = 0; r < 4; r++) {
            int gm = m0 + wave * 32 + sm * 16 + quad * 4 + r;
            float suml = 0.f, sumr = 0.f;
#pragma unroll
            for (int sn = 0; sn < 8; sn++) {
                float v = acc[sm][sn][r] + bias_r[sn];
                suml += v * att_l[sn];
                sumr += v * att_r[sn];
                if (gm < M) {
                    int gn = n0 + sn * 16 + l16;
                    Hb[(size_t)gm * 256 + gn] = bf16round(v);
                }
            }
#pragma unroll
            for (int off = 1; off < 16; off <<= 1) {
                suml += __shfl_xor(suml, off);
                sumr += __shfl_xor(sumr, off);
            }
            if (l16 == 0 && gm < M) {
                al[gm * HEADS + bx] = suml;
                ar[gm * HEADS + bx] = sumr;
            }
        }
}

__global__ __launch_bounds__(256) void gemm_l0(
    const ushort* __restrict__ xb, const ushort* __restrict__ W0b,
    const float* __restrict__ b0,
    const float* __restrict__ attl0, const float* __restrict__ attr0,
    ushort* __restrict__ hb, float* __restrict__ al, float* __restrict__ ar)
{
    __shared__ ushort sA[128 * 32], sB[128 * 32];
    gemm_body(blockIdx.x, blockIdx.y, xb, W0b, b0,
              hb, attl0, attr0, al, ar, N_NODES, 128, sA, sB);
}

__global__ __launch_bounds__(256) void gemm_l1(
    const ushort* __restrict__ Ab, const ushort* __restrict__ Wb,
    const float* __restrict__ bias, ushort* __restrict__ Hb,
    const float* __restrict__ attl, const float* __restrict__ attr,
    float* __restrict__ al, float* __restrict__ ar)
{
    __shared__ ushort sA[128 * 32], sB[128 * 32];
    gemm_body(blockIdx.x, blockIdx.y, Ab, Wb, bias,
              Hb, attl, attr, al, ar, N_NODES, HH, sA, sB);
}

// ---------------- GAT aggregate: one WAVE per dst node, one-pass softmax ------
__global__ __launch_bounds__(256) void gat_aggregate(
    const ushort* __restrict__ hb, const float* __restrict__ al, const float* __restrict__ ar,
    const int* __restrict__ rowptr, const ushort* __restrict__ csr16,
    ushort* __restrict__ outb)
{
    const int node = blockIdx.x * 4 + (threadIdx.x >> 6);
    const int lane = threadIdx.x & 63;
    if (node >= N_NODES) return;
    const int beg = rowptr[node], end = rowptr[node + 1];
    const int half = lane >> 5;
    const int l32  = lane & 31;
    const int headf = l32 >> 4;
    const float2 ard = ((const float2*)ar)[node];

    float dsum0 = 0.f, dsum1 = 0.f;
    float2v av[4];
#pragma unroll
    for (int j = 0; j < 4; j++) av[j] = (float2v)(0.f);

    for (int c0 = beg; c0 < end; c0 += 64) {
        const int n = min(64, end - c0);
        int s = 0; float w0 = 0.f, w1 = 0.f;
        if (lane < n) {
            s = (int)csr16[c0 + lane];
            float2 aa = ((const float2*)al)[s];
            float e0 = aa.x + ard.x;
            float e1 = aa.y + ard.y;
            e0 = fmaxf(e0, 0.f) + 0.2f * fminf(e0, 0.f);
            e1 = fmaxf(e1, 0.f) + 0.2f * fminf(e1, 0.f);
            w0 = __expf(e0); w1 = __expf(e1);
            dsum0 += w0; dsum1 += w1;
        }
        for (int i = 0; i < n; i += 4) {
            int e0i = i + half;
            int   se0 = __shfl(s,  e0i);
            float u00 = __shfl(w0, e0i);
            float u01 = __shfl(w1, e0i);
            float2v we0 = (float2v)(headf ? u01 : u00);
            const uint4 q0 = *(const uint4*)(hb + (size_t)se0 * 256 + l32 * 8);
            int e1i = i + 2 + half;
            int   se1 = __shfl(s,  e1i);
            float u10 = __shfl(w0, e1i);
            float u11 = __shfl(w1, e1i);
            float2v we1 = (float2v)(headf ? u11 : u10);
            const uint4 q1 = *(const uint4*)(hb + (size_t)se1 * 256 + l32 * 8);
            float2v p;
            p.x = __uint_as_float(q0.x << 16); p.y = __uint_as_float(q0.x & 0xFFFF0000u);
            av[0] += we0 * p;
            p.x = __uint_as_float(q0.y << 16); p.y = __uint_as_float(q0.y & 0xFFFF0000u);
            av[1] += we0 * p;
            p.x = __uint_as_float(q0.z << 16); p.y = __uint_as_float(q0.z & 0xFFFF0000u);
            av[2] += we0 * p;
            p.x = __uint_as_float(q0.w << 16); p.y = __uint_as_float(q0.w & 0xFFFF0000u);
            av[3] += we0 * p;
            p.x = __uint_as_float(q1.x << 16); p.y = __uint_as_float(q1.x & 0xFFFF0000u);
            av[0] += we1 * p;
            p.x = __uint_as_float(q1.y << 16); p.y = __uint_as_float(q1.y & 0xFFFF0000u);
            av[1] += we1 * p;
            p.x = __uint_as_float(q1.z << 16); p.y = __uint_as_float(q1.z & 0xFFFF0000u);
            av[2] += we1 * p;
            p.x = __uint_as_float(q1.w << 16); p.y = __uint_as_float(q1.w & 0xFFFF0000u);
            av[3] += we1 * p;
        }
    }
#pragma unroll
    for (int j = 0; j < 4; j++) {
        av[j].x += __shfl_xor(av[j].x, 32);
        av[j].y += __shfl_xor(av[j].y, 32);
    }
#pragma unroll
    for (int off = 32; off; off >>= 1) {
        dsum0 += __shfl_xor(dsum0, off);
        dsum1 += __shfl_xor(dsum1, off);
    }
    if (half == 0) {
        const float den = headf ? dsum1 : dsum0;
        const float inv = (end > beg) ? 1.f / den : 0.f;
        ushort r[8];
#pragma unroll
        for (int j = 0; j < 4; j++) {
            r[2*j]   = bf16round(fmaxf(av[j].x * inv, 0.f));   // ReLU
            r[2*j+1] = bf16round(fmaxf(av[j].y * inv, 0.f));
        }
        *(uint4*)(outb + (size_t)node * 256 + l32 * 8) = *(uint4*)r;
    }
}

// ---------------- fused post_mp + log_softmax (128 rows/block) ----------------
__global__ __launch_bounds__(256) void fused_post(
    const ushort* __restrict__ Ab,   // x2 [MPAD,256] bf16
    const ushort* __restrict__ Bb,   // Wp1 [128,256] bf16
    const float* __restrict__ bp1,
    const ushort* __restrict__ W2b,  // Wp2 padded [64,128] bf16
    const float* __restrict__ bp2,
    float* __restrict__ out, int M)
{
    __shared__ ushort sA[128 * 32];  // A tile / W2 tile
    __shared__ ushort sB[128 * 32];  // Wp1 tile
    __shared__ ushort sP[128 * 136]; // p bf16 (padded stride)

    const int t = threadIdx.x;
    const int wave = t >> 6, lane = t & 63;
    const int quad = lane >> 4, l16 = lane & 15;
    const int rl = lane >> 2, seg = lane & 3;
    const int m0 = blockIdx.x * 128;

    // ---- stage 1: p[128x128] = A @ Wp1^T + bp1 ----
    floatx4 acc[2][8];
#pragma unroll
    for (int i = 0; i < 2; i++)
#pragma unroll
        for (int j = 0; j < 8; j++) acc[i][j] = (floatx4)(0.f);

    for (int k0 = 0; k0 < HH; k0 += 32) {
#pragma unroll
        for (int j = 0; j < 2; j++) {
            int br = wave * 32 + j * 16;
            size_t gro = (size_t)(m0 + br + rl) * HH + k0 + seg * 8;
            gl_lds16(Ab + gro, sA + br * 32);
        }
#pragma unroll
        for (int j = 0; j < 2; j++) {
            int br = wave * 32 + j * 16;
            size_t gro = (size_t)(br + rl) * HH + k0 + seg * 8;
            gl_lds16(Bb + gro, sB + br * 32);
        }
        __syncthreads();
        short8 af[2];
#pragma unroll
        for (int sm = 0; sm < 2; sm++) {
            int r = wave * 32 + sm * 16 + l16;
            af[sm] = *(const short8*)(sA + r * 32 + quad * 8);
        }
#pragma unroll
        for (int sn = 0; sn < 8; sn++) {
            int r = sn * 16 + l16;
            short8 b = *(const short8*)(sB + r * 32 + quad * 8);
#pragma unroll
            for (int sm = 0; sm < 2; sm++)
                acc[sm][sn] = __builtin_amdgcn_mfma_f32_16x16x32_bf16(af[sm], b, acc[sm][sn], 0, 0, 0);
        }
        __syncthreads();
    }
    // write p to LDS (bf16)
#pragma unroll
    for (int sm = 0; sm < 2; sm++)
#pragma unroll
        for (int sn = 0; sn < 8; sn++)
#pragma unroll
            for (int r = 0; r < 4; r++) {
                int row = wave * 32 + sm * 16 + quad * 4 + r;
                int col = sn * 16 + l16;
                sP[row * 136 + col] = bf16round(acc[sm][sn][r] + bp1[col]);
            }
    __syncthreads();

    // ---- stage 2: logits[128x47] = p @ Wp2^T + bp2 ----
    floatx4 acc2[2][4];
#pragma unroll
    for (int i = 0; i < 2; i++)
#pragma unroll
        for (int j = 0; j < 4; j++) acc2[i][j] = (floatx4)(0.f);

    for (int k0 = 0; k0 < HID; k0 += 32) {
        {
            int br = wave * 16;   // 64 rows total across 4 waves
            size_t gro = (size_t)(br + rl) * HID + k0 + seg * 8;
            gl_lds16(W2b + gro, sA + br * 32);
        }
        __syncthreads();
        short8 ph[2];
#pragma unroll
        for (int sm = 0; sm < 2; sm++) {
            int r = wave * 32 + sm * 16 + l16;
            ph[sm] = *(const short8*)(sP + r * 136 + k0 + quad * 8);
        }
#pragma unroll
        for (int sn = 0; sn < 4; sn++) {
            int r = sn * 16 + l16;
            short8 b = *(const short8*)(sA + r * 32 + quad * 8);
#pragma unroll
            for (int sm = 0; sm < 2; sm++)
                acc2[sm][sn] = __builtin_amdgcn_mfma_f32_16x16x32_bf16(ph[sm], b, acc2[sm][sn], 0, 0, 0);
        }
        __syncthreads();
    }

    // ---- bias + log_softmax ----
    float b2[4];
#pragma unroll
    for (int sn = 0; sn < 4; sn++) {
        int n = sn * 16 + l16;
        b2[sn] = (n < OUT_C) ? bp2[n] : 0.f;
    }
#pragma unroll
    for (int sm = 0; sm < 2; sm++)
#pragma unroll
        for (int r = 0; r < 4; r++) {
            float v[4];
            float m = -INFINITY;
#pragma unroll
            for (int sn = 0; sn < 4; sn++) {
                int n = sn * 16 + l16;
                float xv = (n < OUT_C) ? acc2[sm][sn][r] + b2[sn] : -INFINITY;
                v[sn] = xv;
                m = fmaxf(m, xv);
            }
#pragma unroll
            for (int off = 1; off < 16; off <<= 1) m = fmaxf(m, __shfl_xor(m, off));
            float ssum = 0.f;
#pragma unroll
            for (int sn = 0; sn < 4; sn++) {
                int n = sn * 16 + l16;
                if (n < OUT_C) ssum += __expf(v[sn] - m);
            }
#pragma unroll
            for (int off = 1; off < 16; off <<= 1) ssum += __shfl_xor(ssum, off);
            float lse = m + logf(ssum);
            int gm = m0 + wave * 32 + sm * 16 + quad * 4 + r;
            if (gm < M) {
#pragma unroll
                for (int sn = 0; sn < 4; sn++) {
                    int n = sn * 16 + l16;
                    if (n < OUT_C) out[(size_t)gm * OUT_C + n] = v[sn] - lse;
                }
            }
        }
}

extern "C" void kernel_launch(void* const* d_in, const int* in_sizes, int n_in,
                              void* d_out, int out_size, void* d_ws, size_t ws_size,
                              hipStream_t stream) {
    const float* x     = (const float*)d_in[0];
    const int*   ei    = (const int*)d_in[1];
    const float* W0    = (const float*)d_in[2];
    const float* b0    = (const float*)d_in[3];
    const float* attl0 = (const float*)d_in[4];
    const float* attr0 = (const float*)d_in[5];
    const float* W1    = (const float*)d_in[6];
    const float* b1    = (const float*)d_in[7];
    const float* attl1 = (const float*)d_in[8];
    const float* attr1 = (const float*)d_in[9];
    const float* Wp1   = (const float*)d_in[10];
    const float* bp1   = (const float*)d_in[11];
    const float* Wp2   = (const float*)d_in[12];
    const float* bp2   = (const float*)d_in[13];
    float* out = (float*)d_out;

    const int Etot = E_EDGES;
    const int* srcv = ei;
    const int* dstv = ei + Etot;

    char* ws = (char*)d_ws;
    size_t off = 0;
    auto alloc = [&](size_t bytes) -> void* {
        void* p = ws + off;
        off = (off + bytes + 255) & ~(size_t)255;
        return p;
    };
    int*    rowptr = (int*)alloc((size_t)(N_NODES + 1) * sizeof(int));
    int*    deg    = (int*)alloc((size_t)N_NODES * sizeof(int));
    ushort* rank   = (ushort*)alloc((size_t)Etot * 2);
    ushort* csr16  = (ushort*)alloc((size_t)Etot * 2);
    int*    bsum   = (int*)alloc(256 * sizeof(int));
    float*  al     = (float*)alloc((size_t)N_NODES * HEADS * sizeof(float));
    float*  ar     = (float*)alloc((size_t)N_NODES * HEADS * sizeof(float));
    ushort* xb     = (ushort*)alloc((size_t)MPAD * 128 * 2);  // x bf16, K padded
    ushort* W0b    = (ushort*)alloc((size_t)HH * 128 * 2);
    ushort* W1b    = (ushort*)alloc((size_t)HH * HH * 2);
    ushort* Wp1b   = (ushort*)alloc((size_t)HID * HH * 2);
    ushort* Wp2b   = (ushort*)alloc((size_t)64 * HID * 2);    // padded rows
    ushort* hb     = (ushort*)alloc((size_t)N_NODES * HH * 2); // bf16 h (pre-relu)
    ushort* xbb    = (ushort*)alloc((size_t)MPAD * HH * 2);    // agg out (padded)

    // single cooperative dispatch: zero + count/rank + converts + scan + fill
    {
        void* args[] = {
            (void*)&dstv, (void*)&srcv, (void*)&deg, (void*)&rank,
            (void*)&rowptr, (void*)&bsum, (void*)&csr16,
            (void*)&x, (void*)&W0, (void*)&W1, (void*)&Wp1, (void*)&Wp2,
            (void*)&xb, (void*)&W0b, (void*)&W1b, (void*)&Wp1b, (void*)&Wp2b
        };
        hipLaunchCooperativeKernel((void*)csr_build, dim3(NBGRID), dim3(256),
                                   args, 0, stream);
    }

    // L0 GEMM (async bf16 path, Kp=128)
    {
        dim3 g(2, MPAD / 128);
        gemm_l0<<<g, 256, 0, stream>>>(xb, W0b, b0, attl0, attr0, hb, al, ar);
    }

    gat_aggregate<<<(N_NODES + 3) / 4, 256, 0, stream>>>(hb, al, ar, rowptr, csr16, xbb);

    // Layer 1
    {
        dim3 g(2, MPAD / 128);
        gemm_l1<<<g, 256, 0, stream>>>(xbb, W1b, b1, hb, attl1, attr1, al, ar);
    }
    gat_aggregate<<<(N_NODES + 3) / 4, 256, 0, stream>>>(hb, al, ar, rowptr, csr16, xbb);

    // fused post_mp + log_softmax
    fused_post<<<MPAD / 128, 256, 0, stream>>>(xbb, Wp1b, bp1, Wp2b, bp2, out, N_NODES);
}

// Round 14
// 312.397 us; speedup vs baseline: 2.2436x; 2.2436x over previous
//
#include <hip/hip_runtime.h>
#include <math.h>

#define N_NODES 50000
#define E_EDGES 800000
#define F_IN 100
#define HID 128
#define HEADS 2
#define OUT_C 47
#define HH (HEADS*HID)   // 256
#define MPAD 50048       // N_NODES padded to 128-row tiles

typedef float floatx4 __attribute__((ext_vector_type(4)));
typedef float float2v __attribute__((ext_vector_type(2)));
typedef short short8 __attribute__((ext_vector_type(8)));

__device__ inline ushort bf16round(float v) {
    unsigned u = __float_as_uint(v);
    return (ushort)((u + 0x7FFFu + ((u >> 16) & 1u)) >> 16);
}

// async global->LDS, 16B per lane; LDS dest = wave-uniform base + lane*16
__device__ __forceinline__ void gl_lds16(const void* g, void* l) {
    __builtin_amdgcn_global_load_lds(
        (const __attribute__((address_space(1))) unsigned int*)g,
        (__attribute__((address_space(3))) unsigned int*)l, 16, 0, 0);
}

// ---------------- bf16 MFMA GEMM body (128x128 tile), async LDS staging -------
__device__ __forceinline__ void gemm_body(
    int bx, int by,
    const ushort* __restrict__ Ab, const ushort* __restrict__ Wb,
    const float* __restrict__ bias,
    ushort* __restrict__ Hb,
    const float* __restrict__ attl, const float* __restrict__ attr,
    float* __restrict__ al, float* __restrict__ ar,
    int M, int Kp, ushort* sA, ushort* sB)
{
    const int t = threadIdx.x;
    const int wave = t >> 6, lane = t & 63;
    const int quad = lane >> 4, l16 = lane & 15;
    const int rl = lane >> 2, seg = lane & 3;
    const int m0 = by * 128, n0 = bx * 128;

    floatx4 acc[2][8];
#pragma unroll
    for (int i = 0; i < 2; i++)
#pragma unroll
        for (int j = 0; j < 8; j++) acc[i][j] = (floatx4)(0.f);

    for (int k0 = 0; k0 < Kp; k0 += 32) {
#pragma unroll
        for (int j = 0; j < 2; j++) {
            int br = wave * 32 + j * 16;
            size_t gro = (size_t)(m0 + br + rl) * Kp + k0 + seg * 8;
            gl_lds16(Ab + gro, sA + br * 32);
        }
#pragma unroll
        for (int j = 0; j < 2; j++) {
            int br = wave * 32 + j * 16;
            size_t gro = (size_t)(n0 + br + rl) * Kp + k0 + seg * 8;
            gl_lds16(Wb + gro, sB + br * 32);
        }
        __syncthreads();

        short8 af[2];
#pragma unroll
        for (int sm = 0; sm < 2; sm++) {
            int r = wave * 32 + sm * 16 + l16;
            af[sm] = *(const short8*)(sA + r * 32 + quad * 8);
        }
#pragma unroll
        for (int sn = 0; sn < 8; sn++) {
            int r = sn * 16 + l16;
            short8 b = *(const short8*)(sB + r * 32 + quad * 8);
#pragma unroll
            for (int sm = 0; sm < 2; sm++)
                acc[sm][sn] = __builtin_amdgcn_mfma_f32_16x16x32_bf16(af[sm], b, acc[sm][sn], 0, 0, 0);
        }
        __syncthreads();
    }

    // epilogue: C/D layout col=lane&15, row=quad*4+reg; fused alpha scores
    float bias_r[8], att_l[8], att_r[8];
#pragma unroll
    for (int sn = 0; sn < 8; sn++) {
        int ai = n0 + sn * 16 + l16;
        bias_r[sn] = bias[ai];
        att_l[sn] = attl[ai];
        att_r[sn] = attr[ai];
    }
#pragma unroll
    for (int sm = 0; sm < 2; sm++)
#pragma unroll
        for (int r = 0; r < 4; r++) {
            int gm = m0 + wave * 32 + sm * 16 + quad * 4 + r;
            float suml = 0.f, sumr = 0.f;
#pragma unroll
            for (int sn = 0; sn < 8; sn++) {
                float v = acc[sm][sn][r] + bias_r[sn];
                suml += v * att_l[sn];
                sumr += v * att_r[sn];
                if (gm < M) {
                    int gn = n0 + sn * 16 + l16;
                    Hb[(size_t)gm * 256 + gn] = bf16round(v);
                }
            }
#pragma unroll
            for (int off = 1; off < 16; off <<= 1) {
                suml += __shfl_xor(suml, off);
                sumr += __shfl_xor(sumr, off);
            }
            if (l16 == 0 && gm < M) {
                al[gm * HEADS + bx] = suml;
                ar[gm * HEADS + bx] = sumr;
            }
        }
}

__global__ __launch_bounds__(256) void gemm_l0(
    const ushort* __restrict__ xb, const ushort* __restrict__ W0b,
    const float* __restrict__ b0,
    const float* __restrict__ attl0, const float* __restrict__ attr0,
    ushort* __restrict__ hb, float* __restrict__ al, float* __restrict__ ar)
{
    __shared__ ushort sA[128 * 32], sB[128 * 32];
    gemm_body(blockIdx.x, blockIdx.y, xb, W0b, b0,
              hb, attl0, attr0, al, ar, N_NODES, 128, sA, sB);
}

__global__ __launch_bounds__(256) void gemm_l1(
    const ushort* __restrict__ Ab, const ushort* __restrict__ Wb,
    const float* __restrict__ bias, ushort* __restrict__ Hb,
    const float* __restrict__ attl, const float* __restrict__ attr,
    float* __restrict__ al, float* __restrict__ ar)
{
    __shared__ ushort sA[128 * 32], sB[128 * 32];
    gemm_body(blockIdx.x, blockIdx.y, Ab, Wb, bias,
              Hb, attl, attr, al, ar, N_NODES, HH, sA, sB);
}

// ---------------- degree count + rank + all fp32->bf16 converts ----------------
__global__ void count_convert(const int* __restrict__ dstv, int* __restrict__ deg,
                              ushort* __restrict__ rank,
                              const float* __restrict__ x,  const float* __restrict__ W0,
                              const float* __restrict__ W1, const float* __restrict__ Wp1,
                              const float* __restrict__ Wp2,
                              ushort* __restrict__ xb,  ushort* __restrict__ W0b,
                              ushort* __restrict__ W1b, ushort* __restrict__ Wp1b,
                              ushort* __restrict__ Wp2b) {
    const int cx = N_NODES * 32;        // x: 50000 rows x 32 chunks (K padded 100->128)
    const int c0 = cx + 256 * 32;       // W0: 256 rows x 32 chunks
    const int c1 = c0 + (HH * HH) / 4;  // W1
    const int c2 = c1 + (HID * HH) / 4; // Wp1
    const int c3 = c2 + (64 * HID) / 4; // Wp2 (64 padded rows)
    int i = blockIdx.x * 256 + threadIdx.x;
    if (i < E_EDGES) {
        int d = dstv[i];
        rank[i] = (ushort)atomicAdd(&deg[d], 1);
    }
    if (i >= c3) return;
    float4 v = make_float4(0.f, 0.f, 0.f, 0.f);
    ushort* H; size_t o;
    if (i < cx) {
        int row = i >> 5, kc = (i & 31) * 4;
        if (kc < F_IN) v = *(const float4*)(x + (size_t)row * F_IN + kc);
        H = xb; o = (size_t)row * 128 + kc;
    } else if (i < c0) {
        int j = i - cx;
        int row = j >> 5, kc = (j & 31) * 4;
        if (kc < F_IN) v = *(const float4*)(W0 + (size_t)row * F_IN + kc);
        H = W0b; o = (size_t)row * 128 + kc;
    } else if (i < c1) {
        int j = i - c0;
        v = *(const float4*)(W1 + (size_t)j * 4);
        H = W1b; o = (size_t)j * 4;
    } else if (i < c2) {
        int j = i - c1;
        v = *(const float4*)(Wp1 + (size_t)j * 4);
        H = Wp1b; o = (size_t)j * 4;
    } else {
        int j = i - c2;
        int row = j >> 5;                // HID/4 = 32 chunks per row
        if (row < OUT_C) v = *(const float4*)(Wp2 + (size_t)j * 4);
        H = Wp2b; o = (size_t)j * 4;
    }
    ushort4 r;
    r.x = bf16round(v.x); r.y = bf16round(v.y);
    r.z = bf16round(v.z); r.w = bf16round(v.w);
    *(ushort4*)(H + o) = r;
}

// ---------------- CSR scan ----------------
__global__ void scan_local(const int* __restrict__ cnt, int* __restrict__ excl,
                           int* __restrict__ bsum, int Nn) {
    __shared__ int s[256];
    int t = threadIdx.x;
    int i = blockIdx.x * 256 + t;
    int v = (i < Nn) ? cnt[i] : 0;
    s[t] = v;
    __syncthreads();
    for (int off = 1; off < 256; off <<= 1) {
        int add = (t >= off) ? s[t - off] : 0;
        __syncthreads();
        s[t] += add;
        __syncthreads();
    }
    int incl = s[t];
    if (i < Nn) excl[i] = incl - v;
    if (t == 255) bsum[blockIdx.x] = incl;
}

// fused: each block redundantly scans the (<=256) block sums in LDS, then adds.
__global__ void scan_add_fused(int* __restrict__ rowptr, const int* __restrict__ bsum,
                               int Nn, int Etot, int nblk) {
    __shared__ int s[256];
    int t = threadIdx.x;
    s[t] = (t < nblk) ? bsum[t] : 0;
    __syncthreads();
    for (int off = 1; off < 256; off <<= 1) {
        int add = (t >= off) ? s[t - off] : 0;
        __syncthreads();
        s[t] += add;
        __syncthreads();
    }
    int add = (blockIdx.x == 0) ? 0 : s[blockIdx.x - 1];
    int i = blockIdx.x * 256 + t;
    if (i < Nn) rowptr[i] += add;
    if (i == 0) rowptr[Nn] = Etot;
}

// rank-based fill: no atomics, 2B scatter
__global__ void fill_csr16(const int* __restrict__ src, const int* __restrict__ dst,
                           const int* __restrict__ rowptr, const ushort* __restrict__ rank,
                           ushort* __restrict__ csr16, int E) {
    int e = blockIdx.x * 256 + threadIdx.x;
    if (e < E) {
        int pos = rowptr[dst[e]] + (int)rank[e];
        csr16[pos] = (ushort)src[e];
    }
}

// ---------------- GAT aggregate: one WAVE per dst node, one-pass softmax ------
__global__ __launch_bounds__(256) void gat_aggregate(
    const ushort* __restrict__ hb, const float* __restrict__ al, const float* __restrict__ ar,
    const int* __restrict__ rowptr, const ushort* __restrict__ csr16,
    ushort* __restrict__ outb)
{
    const int node = blockIdx.x * 4 + (threadIdx.x >> 6);
    const int lane = threadIdx.x & 63;
    if (node >= N_NODES) return;
    const int beg = rowptr[node], end = rowptr[node + 1];
    const int half = lane >> 5;
    const int l32  = lane & 31;
    const int headf = l32 >> 4;
    const float2 ard = ((const float2*)ar)[node];

    float dsum0 = 0.f, dsum1 = 0.f;
    float2v av[4];
#pragma unroll
    for (int j = 0; j < 4; j++) av[j] = (float2v)(0.f);

    for (int c0 = beg; c0 < end; c0 += 64) {
        const int n = min(64, end - c0);
        int s = 0; float w0 = 0.f, w1 = 0.f;
        if (lane < n) {
            s = (int)csr16[c0 + lane];
            float2 aa = ((const float2*)al)[s];
            float e0 = aa.x + ard.x;
            float e1 = aa.y + ard.y;
            e0 = fmaxf(e0, 0.f) + 0.2f * fminf(e0, 0.f);
            e1 = fmaxf(e1, 0.f) + 0.2f * fminf(e1, 0.f);
            w0 = __expf(e0); w1 = __expf(e1);
            dsum0 += w0; dsum1 += w1;
        }
        for (int i = 0; i < n; i += 4) {
            int e0i = i + half;
            int   se0 = __shfl(s,  e0i);
            float u00 = __shfl(w0, e0i);
            float u01 = __shfl(w1, e0i);
            float2v we0 = (float2v)(headf ? u01 : u00);
            const uint4 q0 = *(const uint4*)(hb + (size_t)se0 * 256 + l32 * 8);
            int e1i = i + 2 + half;
            int   se1 = __shfl(s,  e1i);
            float u10 = __shfl(w0, e1i);
            float u11 = __shfl(w1, e1i);
            float2v we1 = (float2v)(headf ? u11 : u10);
            const uint4 q1 = *(const uint4*)(hb + (size_t)se1 * 256 + l32 * 8);
            float2v p;
            p.x = __uint_as_float(q0.x << 16); p.y = __uint_as_float(q0.x & 0xFFFF0000u);
            av[0] += we0 * p;
            p.x = __uint_as_float(q0.y << 16); p.y = __uint_as_float(q0.y & 0xFFFF0000u);
            av[1] += we0 * p;
            p.x = __uint_as_float(q0.z << 16); p.y = __uint_as_float(q0.z & 0xFFFF0000u);
            av[2] += we0 * p;
            p.x = __uint_as_float(q0.w << 16); p.y = __uint_as_float(q0.w & 0xFFFF0000u);
            av[3] += we0 * p;
            p.x = __uint_as_float(q1.x << 16); p.y = __uint_as_float(q1.x & 0xFFFF0000u);
            av[0] += we1 * p;
            p.x = __uint_as_float(q1.y << 16); p.y = __uint_as_float(q1.y & 0xFFFF0000u);
            av[1] += we1 * p;
            p.x = __uint_as_float(q1.z << 16); p.y = __uint_as_float(q1.z & 0xFFFF0000u);
            av[2] += we1 * p;
            p.x = __uint_as_float(q1.w << 16); p.y = __uint_as_float(q1.w & 0xFFFF0000u);
            av[3] += we1 * p;
        }
    }
#pragma unroll
    for (int j = 0; j < 4; j++) {
        av[j].x += __shfl_xor(av[j].x, 32);
        av[j].y += __shfl_xor(av[j].y, 32);
    }
#pragma unroll
    for (int off = 32; off; off >>= 1) {
        dsum0 += __shfl_xor(dsum0, off);
        dsum1 += __shfl_xor(dsum1, off);
    }
    if (half == 0) {
        const float den = headf ? dsum1 : dsum0;
        const float inv = (end > beg) ? 1.f / den : 0.f;
        ushort r[8];
#pragma unroll
        for (int j = 0; j < 4; j++) {
            r[2*j]   = bf16round(fmaxf(av[j].x * inv, 0.f));   // ReLU
            r[2*j+1] = bf16round(fmaxf(av[j].y * inv, 0.f));
        }
        *(uint4*)(outb + (size_t)node * 256 + l32 * 8) = *(uint4*)r;
    }
}

// ---------------- fused post_mp + log_softmax (128 rows/block) ----------------
__global__ __launch_bounds__(256) void fused_post(
    const ushort* __restrict__ Ab,   // x2 [MPAD,256] bf16
    const ushort* __restrict__ Bb,   // Wp1 [128,256] bf16
    const float* __restrict__ bp1,
    const ushort* __restrict__ W2b,  // Wp2 padded [64,128] bf16
    const float* __restrict__ bp2,
    float* __restrict__ out, int M)
{
    __shared__ ushort sA[128 * 32];  // A tile / W2 tile
    __shared__ ushort sB[128 * 32];  // Wp1 tile
    __shared__ ushort sP[128 * 136]; // p bf16 (padded stride)

    const int t = threadIdx.x;
    const int wave = t >> 6, lane = t & 63;
    const int quad = lane >> 4, l16 = lane & 15;
    const int rl = lane >> 2, seg = lane & 3;
    const int m0 = blockIdx.x * 128;

    // ---- stage 1: p[128x128] = A @ Wp1^T + bp1 ----
    floatx4 acc[2][8];
#pragma unroll
    for (int i = 0; i < 2; i++)
#pragma unroll
        for (int j = 0; j < 8; j++) acc[i][j] = (floatx4)(0.f);

    for (int k0 = 0; k0 < HH; k0 += 32) {
#pragma unroll
        for (int j = 0; j < 2; j++) {
            int br = wave * 32 + j * 16;
            size_t gro = (size_t)(m0 + br + rl) * HH + k0 + seg * 8;
            gl_lds16(Ab + gro, sA + br * 32);
        }
#pragma unroll
        for (int j = 0; j < 2; j++) {
            int br = wave * 32 + j * 16;
            size_t gro = (size_t)(br + rl) * HH + k0 + seg * 8;
            gl_lds16(Bb + gro, sB + br * 32);
        }
        __syncthreads();
        short8 af[2];
#pragma unroll
        for (int sm = 0; sm < 2; sm++) {
            int r = wave * 32 + sm * 16 + l16;
            af[sm] = *(const short8*)(sA + r * 32 + quad * 8);
        }
#pragma unroll
        for (int sn = 0; sn < 8; sn++) {
            int r = sn * 16 + l16;
            short8 b = *(const short8*)(sB + r * 32 + quad * 8);
#pragma unroll
            for (int sm = 0; sm < 2; sm++)
                acc[sm][sn] = __builtin_amdgcn_mfma_f32_16x16x32_bf16(af[sm], b, acc[sm][sn], 0, 0, 0);
        }
        __syncthreads();
    }
    // write p to LDS (bf16)
#pragma unroll
    for (int sm = 0; sm < 2; sm++)
#pragma unroll
        for (int sn = 0; sn < 8; sn++)
#pragma unroll
            for (int r = 0; r < 4; r++) {
                int row = wave * 32 + sm * 16 + quad * 4 + r;
                int col = sn * 16 + l16;
                sP[row * 136 + col] = bf16round(acc[sm][sn][r] + bp1[col]);
            }
    __syncthreads();

    // ---- stage 2: logits[128x47] = p @ Wp2^T + bp2 ----
    floatx4 acc2[2][4];
#pragma unroll
    for (int i = 0; i < 2; i++)
#pragma unroll
        for (int j = 0; j < 4; j++) acc2[i][j] = (floatx4)(0.f);

    for (int k0 = 0; k0 < HID; k0 += 32) {
        {
            int br = wave * 16;   // 64 rows total across 4 waves
            size_t gro = (size_t)(br + rl) * HID + k0 + seg * 8;
            gl_lds16(W2b + gro, sA + br * 32);
        }
        __syncthreads();
        short8 ph[2];
#pragma unroll
        for (int sm = 0; sm < 2; sm++) {
            int r = wave * 32 + sm * 16 + l16;
            ph[sm] = *(const short8*)(sP + r * 136 + k0 + quad * 8);
        }
#pragma unroll
        for (int sn = 0; sn < 4; sn++) {
            int r = sn * 16 + l16;
            short8 b = *(const short8*)(sA + r * 32 + quad * 8);
#pragma unroll
            for (int sm = 0; sm < 2; sm++)
                acc2[sm][sn] = __builtin_amdgcn_mfma_f32_16x16x32_bf16(ph[sm], b, acc2[sm][sn], 0, 0, 0);
        }
        __syncthreads();
    }

    // ---- bias + log_softmax ----
    float b2[4];
#pragma unroll
    for (int sn = 0; sn < 4; sn++) {
        int n = sn * 16 + l16;
        b2[sn] = (n < OUT_C) ? bp2[n] : 0.f;
    }
#pragma unroll
    for (int sm = 0; sm < 2; sm++)
#pragma unroll
        for (int r = 0; r < 4; r++) {
            float v[4];
            float m = -INFINITY;
#pragma unroll
            for (int sn = 0; sn < 4; sn++) {
                int n = sn * 16 + l16;
                float xv = (n < OUT_C) ? acc2[sm][sn][r] + b2[sn] : -INFINITY;
                v[sn] = xv;
                m = fmaxf(m, xv);
            }
#pragma unroll
            for (int off = 1; off < 16; off <<= 1) m = fmaxf(m, __shfl_xor(m, off));
            float ssum = 0.f;
#pragma unroll
            for (int sn = 0; sn < 4; sn++) {
                int n = sn * 16 + l16;
                if (n < OUT_C) ssum += __expf(v[sn] - m);
            }
#pragma unroll
            for (int off = 1; off < 16; off <<= 1) ssum += __shfl_xor(ssum, off);
            float lse = m + logf(ssum);
            int gm = m0 + wave * 32 + sm * 16 + quad * 4 + r;
            if (gm < M) {
#pragma unroll
                for (int sn = 0; sn < 4; sn++) {
                    int n = sn * 16 + l16;
                    if (n < OUT_C) out[(size_t)gm * OUT_C + n] = v[sn] - lse;
                }
            }
        }
}

extern "C" void kernel_launch(void* const* d_in, const int* in_sizes, int n_in,
                              void* d_out, int out_size, void* d_ws, size_t ws_size,
                              hipStream_t stream) {
    const float* x     = (const float*)d_in[0];
    const int*   ei    = (const int*)d_in[1];
    const float* W0    = (const float*)d_in[2];
    const float* b0    = (const float*)d_in[3];
    const float* attl0 = (const float*)d_in[4];
    const float* attr0 = (const float*)d_in[5];
    const float* W1    = (const float*)d_in[6];
    const float* b1    = (const float*)d_in[7];
    const float* attl1 = (const float*)d_in[8];
    const float* attr1 = (const float*)d_in[9];
    const float* Wp1   = (const float*)d_in[10];
    const float* bp1   = (const float*)d_in[11];
    const float* Wp2   = (const float*)d_in[12];
    const float* bp2   = (const float*)d_in[13];
    float* out = (float*)d_out;

    const int Nn = N_NODES, Etot = E_EDGES;
    const int* srcv = ei;
    const int* dstv = ei + Etot;

    char* ws = (char*)d_ws;
    size_t off = 0;
    auto alloc = [&](size_t bytes) -> void* {
        void* p = ws + off;
        off = (off + bytes + 255) & ~(size_t)255;
        return p;
    };
    int*    rowptr = (int*)alloc((size_t)(Nn + 1) * sizeof(int));
    int*    deg    = (int*)alloc((size_t)Nn * sizeof(int));
    ushort* rank   = (ushort*)alloc((size_t)Etot * 2);
    ushort* csr16  = (ushort*)alloc((size_t)Etot * 2);
    int*    bsum   = (int*)alloc(256 * sizeof(int));
    float*  al     = (float*)alloc((size_t)Nn * HEADS * sizeof(float));
    float*  ar     = (float*)alloc((size_t)Nn * HEADS * sizeof(float));
    ushort* xb     = (ushort*)alloc((size_t)MPAD * 128 * 2);  // x bf16, K padded
    ushort* W0b    = (ushort*)alloc((size_t)HH * 128 * 2);
    ushort* W1b    = (ushort*)alloc((size_t)HH * HH * 2);
    ushort* Wp1b   = (ushort*)alloc((size_t)HID * HH * 2);
    ushort* Wp2b   = (ushort*)alloc((size_t)64 * HID * 2);    // padded rows
    ushort* hb     = (ushort*)alloc((size_t)Nn * HH * 2);     // bf16 h (pre-relu)
    ushort* xbb    = (ushort*)alloc((size_t)MPAD * HH * 2);   // agg out (padded rows)

    const int nblk = (Nn + 255) / 256;

    hipMemsetAsync(deg, 0, (size_t)Nn * sizeof(int), stream);

    // degree count + rank + all converts (x, W0 padded; W1/Wp1/Wp2)
    {
        const int tot = N_NODES * 32 + 256 * 32 + (HH * HH) / 4 + (HID * HH) / 4 + (64 * HID) / 4;
        const int grid = (tot + 255) / 256;   // > E/256, covers edges too
        count_convert<<<grid, 256, 0, stream>>>(
            dstv, deg, rank, x, W0, W1, Wp1, Wp2, xb, W0b, W1b, Wp1b, Wp2b);
    }

    // L0 GEMM (async bf16 path, Kp=128)
    {
        dim3 g(2, MPAD / 128);
        gemm_l0<<<g, 256, 0, stream>>>(xb, W0b, b0, attl0, attr0, hb, al, ar);
    }

    // CSR scan + rank-based fill (no atomics)
    scan_local<<<nblk, 256, 0, stream>>>(deg, rowptr, bsum, Nn);
    scan_add_fused<<<nblk, 256, 0, stream>>>(rowptr, bsum, Nn, Etot, nblk);
    fill_csr16<<<(Etot + 255) / 256, 256, 0, stream>>>(srcv, dstv, rowptr, rank, csr16, Etot);

    gat_aggregate<<<(Nn + 3) / 4, 256, 0, stream>>>(hb, al, ar, rowptr, csr16, xbb);

    // Layer 1
    {
        dim3 g(2, MPAD / 128);
        gemm_l1<<<g, 256, 0, stream>>>(xbb, W1b, b1, hb, attl1, attr1, al, ar);
    }
    gat_aggregate<<<(Nn + 3) / 4, 256, 0, stream>>>(hb, al, ar, rowptr, csr16, xbb);

    // fused post_mp + log_softmax
    fused_post<<<MPAD / 128, 256, 0, stream>>>(xbb, Wp1b, bp1, Wp2b, bp2, out, Nn);
}